// Round 2
// baseline (335.130 us; speedup 1.0000x reference)
//
#include <hip/hip_runtime.h>
#include <hip/hip_fp16.h>

// GAT (3-layer) on MI355X. N=50000 nodes, E=800000 edges, D=64, H=2/2/1.
// R8: (a) k_agg pass-2 rewritten: wave = 4x16 (H=2) / 8x8 (H=1) lane-groups,
//     each group gathers a different edge's row as uint4 (16B/lane) -> 4-8x
//     fewer VMEM insts, no readlane; src-ptr + alpha broadcast via ds_bpermute;
//     partials combined by shfl_xor butterfly. (b) fhb stored f16 (not bf16):
//     gather MAC becomes cvt+fma -> v_fma_mix, no unpack bitops (hb for the
//     next layer's MFMA stays bf16, separate buffer). (c) k_embed fused into
//     GEMM0 A-load (h0 rows read exactly once). R7 counters: k_agg VALU 57%,
//     HBM 37% -> mixed VALU/latency bound; ~7 wave-inst/edge -> ~3.5.

typedef __attribute__((ext_vector_type(8))) short short8;   // 8 bf16 (4 VGPRs)
typedef __attribute__((ext_vector_type(4))) float float4v;  // 4 fp32 acc

__device__ __forceinline__ float lrelu(float x){ return fmaxf(x, 0.2f*x); }

__device__ __forceinline__ unsigned short f2bf(float f){   // RNE round
  unsigned int u = __float_as_uint(f);
  u += 0x7fffu + ((u >> 16) & 1u);
  return (unsigned short)(u >> 16);
}
__device__ __forceinline__ unsigned short f2h(float f){
  return __half_as_ushort(__float2half(f));
}
__device__ __forceinline__ float2 h2f2(unsigned v){        // 2 f16 -> 2 f32
  __half2 h = *reinterpret_cast<__half2*>(&v);
  return __half22float2(h);
}
__device__ __forceinline__ int bperm(int idx, int v){
  return __builtin_amdgcn_ds_bpermute(idx, v);
}
__device__ __forceinline__ float bperm_f(int idx, int v){
  return __int_as_float(__builtin_amdgcn_ds_bpermute(idx, v));
}

__global__ void k_zero_i32(int* __restrict__ p, int n){
  int i = blockIdx.x*blockDim.x + threadIdx.x;
  if (i < n) p[i] = 0;
}

// hist + rank in one atomic: rank[i] = position of edge i within its dst bucket
__global__ void k_hist_rank(const int* __restrict__ dst, int* __restrict__ counts,
                            int* __restrict__ rank, int E){
  int i = blockIdx.x*blockDim.x + threadIdx.x;
  if (i < E){
    int d = dst[i];
    rank[i] = atomicAdd(&counts[d], 1);
  }
}

__global__ void k_scan_local(const int* __restrict__ counts, int* __restrict__ row_ptr,
                             int* __restrict__ bsum, int N){
  __shared__ int s[256];
  int t = threadIdx.x, g = blockIdx.x*256 + t;
  int v = (g < N) ? counts[g] : 0;
  s[t] = v; __syncthreads();
  #pragma unroll
  for (int off = 1; off < 256; off <<= 1){
    int x = 0;
    if (t >= off) x = s[t-off];
    __syncthreads();
    s[t] += x;
    __syncthreads();
  }
  if (g < N) row_ptr[g+1] = s[t];
  if (g == 0 && t == 0) row_ptr[0] = 0;
  if (t == 255) bsum[blockIdx.x] = s[255];
}

__global__ void k_scan_top(int* __restrict__ bsum, int nb){
  __shared__ int s[256];
  int t = threadIdx.x;
  int v = (t < nb) ? bsum[t] : 0;
  s[t] = v; __syncthreads();
  #pragma unroll
  for (int off = 1; off < 256; off <<= 1){
    int x = 0;
    if (t >= off) x = s[t-off];
    __syncthreads();
    s[t] += x;
    __syncthreads();
  }
  if (t < nb) bsum[t] = s[t] - v;  // exclusive block offsets
}

__global__ void k_scan_fix(int* __restrict__ row_ptr, const int* __restrict__ bsum, int N){
  int g = blockIdx.x*256 + threadIdx.x;
  if (g < N && blockIdx.x > 0) row_ptr[g+1] += bsum[blockIdx.x];
}

// atomic-free scatter: pos comes from rank captured during hist
__global__ void k_scatter2(const int* __restrict__ src, const int* __restrict__ dst,
                           const int* __restrict__ rank, const int* __restrict__ row_ptr,
                           int* __restrict__ ssrc, int E){
  int i = blockIdx.x*blockDim.x + threadIdx.x;
  if (i < E) ssrc[row_ptr[dst[i]] + rank[i]] = src[i];
}

// All three weight preps in one launch.
// Wt layout: [n][IN] bf16 (n-major). W0: 64x128; W1: 128x128; W2|rW2: 128x(64+64).
__global__ void k_wprep_all(const float* __restrict__ W0, const float* __restrict__ W1,
                            const float* __restrict__ W2, const float* __restrict__ rW2,
                            unsigned short* __restrict__ Wt0, unsigned short* __restrict__ Wt1,
                            unsigned short* __restrict__ Wt2){
  int id = blockIdx.x*256 + threadIdx.x;
  if (id < 128*64){
    int n = id/64, k = id%64;
    Wt0[n*64 + k] = f2bf(W0[k*128 + n]);
  } else if (id < 128*64 + 128*128){
    int i = id - 128*64; int n = i/128, k = i%128;
    Wt1[n*128 + k] = f2bf(W1[k*128 + n]);
  } else if (id < 128*64 + 2*128*128){
    int i = id - 128*64 - 128*128; int n = i/128, k = i%128;
    float v = (n < 64) ? W2[k*64 + n] : rW2[k*64 + (n - 64)];
    Wt2[n*128 + k] = f2bf(v);
  }
}

// MFMA GEMM: fhb[N][128](f16 row-major) = A[N][IN] @ W(128 cols via Wt).
// A source: hb bf16 (EMBED=false) or emb[feat[n]]*fv[n] converted on the fly
// (EMBED=true, IN==64). Block 256 thr = 4 waves; wave: 16 rows x 128 cols.
// Layouts (verified): A[m=lane&15][k=quad*8+j]; B[k=quad*8+j][n=lane&15];
// D: col=lane&15, row=quad*4+reg. el/er fused (16-lane butterfly per quad).
template<int IN, int H, bool EMBED>
__global__ __launch_bounds__(256) void k_gemm_mfma(
    const unsigned short* __restrict__ hb,   // [N][IN] bf16 (unused if EMBED)
    const int* __restrict__ feat, const float* __restrict__ fv,
    const float* __restrict__ embp,          // [VOCAB][64] f32
    const unsigned short* __restrict__ Wt,   // [128][IN] bf16, n-major
    const float* __restrict__ al, const float* __restrict__ ar,
    unsigned short* __restrict__ fhb,        // [N][128] f16
    float* __restrict__ elr, int N){
  constexpr int KS = IN/32;
  constexpr int LDP = IN + 8;                // +8 bf16 pad: 2-way banks only
  __shared__ unsigned short Wt_s[128*LDP];
  const int t = threadIdx.x;
  const int lane = t & 63, wid = t >> 6;
  const int l15 = lane & 15, quad = lane >> 4;
  const int row0 = blockIdx.x*64 + wid*16;

  // stage Wt -> LDS (uint4 = 8 bf16)
  for (int id = t; id < 128*(IN/8); id += 256){
    int r = id/(IN/8), seg = id%(IN/8);
    ((uint4*)(Wt_s + r*LDP))[seg] = ((const uint4*)(Wt + (size_t)r*IN))[seg];
  }
  // A fragments from global (overlaps LDS staging)
  short8 a[KS];
  int arow = row0 + l15;
  if (EMBED){
    if (arow < N){
      const float* er2 = embp + (size_t)feat[arow]*64;
      float sc = fv[arow];
      #pragma unroll
      for (int s = 0; s < KS; s++){
        const float4* p = (const float4*)(er2 + s*32 + quad*8);
        float4 v0 = p[0], v1 = p[1];
        short8 ta;
        ta[0] = (short)f2bf(v0.x*sc); ta[1] = (short)f2bf(v0.y*sc);
        ta[2] = (short)f2bf(v0.z*sc); ta[3] = (short)f2bf(v0.w*sc);
        ta[4] = (short)f2bf(v1.x*sc); ta[5] = (short)f2bf(v1.y*sc);
        ta[6] = (short)f2bf(v1.z*sc); ta[7] = (short)f2bf(v1.w*sc);
        a[s] = ta;
      }
    } else {
      #pragma unroll
      for (int s = 0; s < KS; s++) a[s] = short8{0,0,0,0,0,0,0,0};
    }
  } else {
    #pragma unroll
    for (int s = 0; s < KS; s++){
      if (arow < N) a[s] = *(const short8*)(hb + (size_t)arow*IN + s*32 + quad*8);
      else          a[s] = short8{0,0,0,0,0,0,0,0};
    }
  }
  __syncthreads();

  float4v acc[8];
  #pragma unroll
  for (int nt = 0; nt < 8; nt++) acc[nt] = float4v{0.f,0.f,0.f,0.f};
  #pragma unroll
  for (int nt = 0; nt < 8; nt++){
    #pragma unroll
    for (int s = 0; s < KS; s++){
      short8 b = *(const short8*)(Wt_s + (nt*16 + l15)*LDP + s*32 + quad*8);
      acc[nt] = __builtin_amdgcn_mfma_f32_16x16x32_bf16(a[s], b, acc[nt], 0, 0, 0);
    }
  }

  // al/ar at this lane's columns (col = nt*16 + l15); H==1: heads>0 are zero
  float alc[8], arc[8];
  #pragma unroll
  for (int nt = 0; nt < 8; nt++){
    bool hv = (H == 2) || (nt < 4);
    alc[nt] = hv ? al[nt*16 + l15] : 0.f;
    arc[nt] = hv ? ar[nt*16 + l15] : 0.f;
  }
  #pragma unroll
  for (int reg = 0; reg < 4; reg++){
    int row = row0 + quad*4 + reg;
    bool rv = row < N;
    if (rv){
      #pragma unroll
      for (int nt = 0; nt < 8; nt++)
        fhb[(size_t)row*128 + nt*16 + l15] = f2h(acc[nt][reg]);
    }
    float pel0 = 0.f, per0 = 0.f, pel1 = 0.f, per1 = 0.f;
    #pragma unroll
    for (int nt = 0; nt < 4; nt++){
      pel0 += acc[nt][reg]*alc[nt];     per0 += acc[nt][reg]*arc[nt];
      pel1 += acc[nt+4][reg]*alc[nt+4]; per1 += acc[nt+4][reg]*arc[nt+4];
    }
    #pragma unroll
    for (int off = 1; off < 16; off <<= 1){   // reduce across the 16 lanes of a quad
      pel0 += __shfl_xor(pel0, off, 64);
      pel1 += __shfl_xor(pel1, off, 64);
      per0 += __shfl_xor(per0, off, 64);
      per1 += __shfl_xor(per1, off, 64);
    }
    if (l15 == 0 && rv){
      elr[row*4+0] = pel0;
      elr[row*4+1] = (H == 2) ? pel1 : 0.f;
      elr[row*4+2] = per0;
      elr[row*4+3] = (H == 2) ? per1 : 0.f;
    }
  }
}

// One wave per dst node. Pass 1: flat exp-sum (no max; logits bounded, clamp 30).
// Pass 2: wave splits into G lane-groups (H=2: 4x16, H=1: 8x8); each group
// handles one edge per step, each lane gathering a uint4 (8 f16 cols) of the
// src row. Row id + alpha broadcast via ds_bpermute; MAC is v_fma_mix (f16
// source). Per-lane partials are summed across groups by shfl_xor butterfly.
template<int H>
__global__ __launch_bounds__(256) void k_agg(
    const unsigned short* __restrict__ fhb,  // [N][128] f16
    const float* __restrict__ elr,
    const int* __restrict__ row_ptr, const int* __restrict__ ssrc,
    const float* __restrict__ bias, const float* __restrict__ res,
    int act, int res_from_fh,
    float* __restrict__ out, int out_ld, unsigned* __restrict__ outb, int N){
  int lane = threadIdx.x & 63, wid = threadIdx.x >> 6;
  int n = blockIdx.x*4 + wid;
  if (n >= N) return;
  int beg = row_ptr[n], end = row_ptr[n+1];
  float er0 = elr[n*4+2];
  float er1 = (H == 2) ? elr[n*4+3] : 0.f;

  // pass 1: numerators + denominator (softmax is shift-invariant; no max needed)
  float x0 = 0.f, x1 = 0.f;
  int s_first = 0;
  {
    int i = beg + lane;
    if (i < end){
      s_first = ssrc[i];
      float2 el = *(const float2*)(elr + s_first*4);
      x0 = __expf(fminf(lrelu(el.x + er0), 30.f));
      if (H == 2) x1 = __expf(fminf(lrelu(el.y + er1), 30.f));
    }
  }
  float d0 = x0, d1 = x1;
  for (int i = beg + lane + 64; i < end; i += 64){
    int s = ssrc[i];
    float2 el = *(const float2*)(elr + s*4);
    d0 += __expf(fminf(lrelu(el.x + er0), 30.f));
    if (H == 2) d1 += __expf(fminf(lrelu(el.y + er1), 30.f));
  }
  #pragma unroll
  for (int off = 32; off >= 1; off >>= 1){       // add-only butterfly
    d0 += __shfl_xor(d0, off, 64);
    if (H == 2) d1 += __shfl_xor(d1, off, 64);
  }
  float rd0 = d0 > 0.f ? 1.f/d0 : 0.f;
  float rd1 = (H == 2 && d1 > 0.f) ? 1.f/d1 : 0.f;

  // pass 2
  const uint4* fh4 = (const uint4*)fhb;          // row = 16 uint4 (128 f16)
  const int g = (H == 2) ? (lane >> 4) : (lane >> 3);
  const int c = (H == 2) ? (lane & 15) : (lane & 7);
  const int head32 = (H == 2 && c >= 8) ? 32 : 0;
  float acc[8];
  #pragma unroll
  for (int k = 0; k < 8; k++) acc[k] = 0.f;

  for (int base = beg; base < end; base += 64){
    // per-lane s / scaled alpha for this 64-edge window
    int s = 0; float a0 = 0.f, a1 = 0.f;
    {
      int i = base + lane;
      if (i < end){
        if (base == beg){
          s = s_first;
          a0 = x0 * rd0; if (H == 2) a1 = x1 * rd1;
        } else {
          s = ssrc[i];
          float2 el = *(const float2*)(elr + s*4);
          a0 = __expf(fminf(lrelu(el.x + er0), 30.f)) * rd0;
          if (H == 2) a1 = __expf(fminf(lrelu(el.y + er1), 30.f)) * rd1;
        }
      }
    }
    int cnt = min(64, end - base);
    if (H == 2){
      // packed alphas: ap = edges 0..31 (lanes<32: a0, lanes>=32: a1), ap2 = 32..63
      float a1x = __shfl_xor(a1, 32, 64);
      float a0x = __shfl_xor(a0, 32, 64);
      int ap  = __float_as_int((lane < 32) ? a0  : a1x);
      int ap2 = __float_as_int((lane < 32) ? a0x : a1);
      for (int j0 = 0; j0 < cnt; j0 += 8){       // 8 edges per step (2 sub-batches of 4)
        int apx = (j0 < 32) ? ap : ap2;          // batch never straddles the 32-boundary
        int jb = j0 & 31;
        int sj[2]; uint4 w[2]; float aj[2];
        #pragma unroll
        for (int u = 0; u < 2; u++) sj[u] = bperm((j0 + 4*u + g) << 2, s);
        #pragma unroll
        for (int u = 0; u < 2; u++) w[u] = fh4[(size_t)(unsigned)sj[u]*16 + c];
        #pragma unroll
        for (int u = 0; u < 2; u++) aj[u] = bperm_f((head32 + jb + 4*u + g) << 2, apx);
        #pragma unroll
        for (int u = 0; u < 2; u++){
          const unsigned* wp = (const unsigned*)&w[u];
          #pragma unroll
          for (int q = 0; q < 4; q++){
            float2 f = h2f2(wp[q]);
            acc[2*q]   = fmaf(f.x, aj[u], acc[2*q]);
            acc[2*q+1] = fmaf(f.y, aj[u], acc[2*q+1]);
          }
        }
      }
    } else {
      int av = __float_as_int(a0);
      for (int j0 = 0; j0 < cnt; j0 += 8){       // 8 edges per step (8 groups of 8 lanes)
        int sj = bperm((j0 + g) << 2, s);
        uint4 w = fh4[(size_t)(unsigned)sj*16 + c];
        float aj = bperm_f((j0 + g) << 2, av);
        const unsigned* wp = (const unsigned*)&w;
        #pragma unroll
        for (int q = 0; q < 4; q++){
          float2 f = h2f2(wp[q]);
          acc[2*q]   = fmaf(f.x, aj, acc[2*q]);
          acc[2*q+1] = fmaf(f.y, aj, acc[2*q+1]);
        }
      }
    }
  }

  // combine group partials: same c across groups holds the same columns
  #pragma unroll
  for (int k = 0; k < 8; k++){
    if (H == 1) acc[k] += __shfl_xor(acc[k], 8, 64);
    acc[k] += __shfl_xor(acc[k], 16, 64);
    acc[k] += __shfl_xor(acc[k], 32, 64);
  }

  // epilogue: lane cc < 16 (H=2) / < 8 (H=1) owns cols cc*8..cc*8+7
  if (H == 2){
    if (lane < 16){
      int cc = lane;
      float o[8];
      const float4* b4 = (const float4*)bias;
      float4 ba = b4[cc*2], bb = b4[cc*2+1];
      o[0]=acc[0]+ba.x; o[1]=acc[1]+ba.y; o[2]=acc[2]+ba.z; o[3]=acc[3]+ba.w;
      o[4]=acc[4]+bb.x; o[5]=acc[5]+bb.y; o[6]=acc[6]+bb.z; o[7]=acc[7]+bb.w;
      if (res){
        const float4* r4 = (const float4*)(res + (size_t)n*128);
        float4 ra = r4[cc*2], rb = r4[cc*2+1];
        o[0]+=ra.x; o[1]+=ra.y; o[2]+=ra.z; o[3]+=ra.w;
        o[4]+=rb.x; o[5]+=rb.y; o[6]+=rb.z; o[7]+=rb.w;
      }
      if (act){
        #pragma unroll
        for (int k = 0; k < 8; k++) o[k] = o[k] > 0.f ? o[k] : expm1f(o[k]);
      }
      if (out){
        float4* o4 = (float4*)(out + (size_t)n*out_ld);
        o4[cc*2]   = make_float4(o[0], o[1], o[2], o[3]);
        o4[cc*2+1] = make_float4(o[4], o[5], o[6], o[7]);
      }
      if (outb){
        uint4 ob;
        ob.x = (unsigned)f2bf(o[0]) | ((unsigned)f2bf(o[1]) << 16);
        ob.y = (unsigned)f2bf(o[2]) | ((unsigned)f2bf(o[3]) << 16);
        ob.z = (unsigned)f2bf(o[4]) | ((unsigned)f2bf(o[5]) << 16);
        ob.w = (unsigned)f2bf(o[6]) | ((unsigned)f2bf(o[7]) << 16);
        *(uint4*)(outb + (size_t)n*64 + cc*4) = ob;
      }
    }
  } else {
    if (lane < 8){
      int cc = lane;
      float o[8];
      #pragma unroll
      for (int k = 0; k < 8; k++) o[k] = acc[k] + bias[cc*8 + k];
      if (res_from_fh){
        uint4 r = fh4[(size_t)n*16 + 8 + cc];    // cols 64..127 = projected residual
        const unsigned* rp = (const unsigned*)&r;
        #pragma unroll
        for (int q = 0; q < 4; q++){
          float2 f = h2f2(rp[q]);
          o[2*q] += f.x; o[2*q+1] += f.y;
        }
      }
      float4* o4 = (float4*)(out + (size_t)n*out_ld);
      o4[cc*2]   = make_float4(o[0], o[1], o[2], o[3]);
      o4[cc*2+1] = make_float4(o[4], o[5], o[6], o[7]);
    }
  }
}

extern "C" void kernel_launch(void* const* d_in, const int* in_sizes, int n_in,
                              void* d_out, int out_size, void* d_ws, size_t ws_size,
                              hipStream_t stream) {
  const int*   feat = (const int*)  d_in[0];
  const float* fv   = (const float*)d_in[1];
  const int*   src  = (const int*)  d_in[2];
  const int*   dst  = (const int*)  d_in[3];
  const float* emb  = (const float*)d_in[4];
  const float* W0   = (const float*)d_in[5];
  const float* al0  = (const float*)d_in[6];
  const float* ar0  = (const float*)d_in[7];
  const float* b0   = (const float*)d_in[8];
  const float* W1   = (const float*)d_in[9];
  const float* al1  = (const float*)d_in[10];
  const float* ar1  = (const float*)d_in[11];
  const float* b1   = (const float*)d_in[12];
  const float* W2   = (const float*)d_in[13];
  const float* al2  = (const float*)d_in[14];
  const float* ar2  = (const float*)d_in[15];
  const float* b2   = (const float*)d_in[16];
  const float* rW2  = (const float*)d_in[17];
  const int N = in_sizes[0] / 8;   // 50000
  const int E = in_sizes[2];       // 800000

  size_t off = 0;
  auto alloc = [&](size_t bytes) -> void* {
    void* p = (char*)d_ws + off;
    off = (off + bytes + 255) & ~(size_t)255;
    return p;
  };
  unsigned short* P1 = (unsigned short*)alloc((size_t)N*128*sizeof(unsigned short)); // fhb f16
  float* P2     = (float*)alloc((size_t)N*128*sizeof(float));                        // layer0 out (res for layer1)
  unsigned short* hb = (unsigned short*)alloc((size_t)N*128*sizeof(unsigned short)); // h bf16
  float* elr    = (float*)alloc((size_t)N*4*sizeof(float));
  int* row_ptr  = (int*)alloc((size_t)(N+1)*sizeof(int));
  int* counts   = (int*)alloc((size_t)N*sizeof(int));
  int* rank     = (int*)alloc((size_t)E*sizeof(int));
  int* ssrc     = (int*)alloc((size_t)E*sizeof(int));
  int* bsum     = (int*)alloc(256*sizeof(int));
  unsigned short* Wt0 = (unsigned short*)alloc((size_t)128*64*sizeof(unsigned short));
  unsigned short* Wt1 = (unsigned short*)alloc((size_t)128*128*sizeof(unsigned short));
  unsigned short* Wt2 = (unsigned short*)alloc((size_t)128*128*sizeof(unsigned short));

  int nb1 = (N + 255) / 256;
  // CSR build (rank captured in hist atomic; scatter atomic-free)
  k_zero_i32<<<(N + 255)/256, 256, 0, stream>>>(counts, N);
  k_hist_rank<<<(E + 255)/256, 256, 0, stream>>>(dst, counts, rank, E);
  k_scan_local<<<nb1, 256, 0, stream>>>(counts, row_ptr, bsum, N);
  k_scan_top<<<1, 256, 0, stream>>>(bsum, nb1);
  k_scan_fix<<<nb1, 256, 0, stream>>>(row_ptr, bsum, N);
  k_scatter2<<<(E + 255)/256, 256, 0, stream>>>(src, dst, rank, row_ptr, ssrc, E);
  // weight transpose+bf16 prep (single launch)
  k_wprep_all<<<(128*64 + 2*128*128 + 255)/256, 256, 0, stream>>>(
      W0, W1, W2, rW2, Wt0, Wt1, Wt2);

  int gt = (N + 63)/64;
  int nagg = (N + 3)/4;
  // layer 0: in=64, H=2, embed fused into A-load, no residual, elu
  k_gemm_mfma<64,2,true><<<gt, 256, 0, stream>>>(nullptr, feat, fv, emb,
                                                 Wt0, al0, ar0, P1, elr, N);
  k_agg<2><<<nagg, 256, 0, stream>>>(P1, elr, row_ptr, ssrc, b0, nullptr,
                                     1, 0, P2, 128, (unsigned*)hb, N);
  // layer 1: in=128, H=2, identity residual, elu; float out unused -> skip store
  k_gemm_mfma<128,2,false><<<gt, 256, 0, stream>>>(hb, nullptr, nullptr, nullptr,
                                                   Wt1, al1, ar1, P1, elr, N);
  k_agg<2><<<nagg, 256, 0, stream>>>(P1, elr, row_ptr, ssrc, b1, P2,
                                     1, 0, nullptr, 128, (unsigned*)hb, N);
  // layer 2: in=128, H=1, projected residual (fh cols 64..127 = h@resW2), no act
  k_gemm_mfma<128,1,false><<<gt, 256, 0, stream>>>(hb, nullptr, nullptr, nullptr,
                                                   Wt2, al2, ar2, P1, elr, N);
  k_agg<1><<<nagg, 256, 0, stream>>>(P1, elr, row_ptr, ssrc, b2, nullptr,
                                     0, 1, (float*)d_out, 64, nullptr, N);
}

// Round 3
// 331.969 us; speedup vs baseline: 1.0095x; 1.0095x over previous
//
#include <hip/hip_runtime.h>
#include <hip/hip_fp16.h>

// GAT (3-layer) on MI355X. N=50000 nodes, E=800000 edges, D=64, H=2/2/1.
// R9: k_agg rewritten SINGLE-PASS: softmax normalization is a per-node scalar,
//     so accumulate unnormalized sum(ex*F) and den=sum(ex) in one pass over
//     edges, divide in the epilogue. Deletes pass-1 (ssrc+elr re-read, 2x exp
//     per edge). Also: 32-bit gather addressing (sj<<8|c*16, saddr form; was
//     v_mad_u64 chains), MAC written as fmaf((float)half,...) for v_fma_mix
//     fusion, expm1f -> __expf-1 (libm call gone), step-4 gather granularity
//     (less tail padding). R8 counters: k_agg VALU 83%, HBM 33% -> VALU-bound.

typedef __attribute__((ext_vector_type(8))) short short8;   // 8 bf16 (4 VGPRs)
typedef __attribute__((ext_vector_type(4))) float float4v;  // 4 fp32 acc

__device__ __forceinline__ float lrelu(float x){ return fmaxf(x, 0.2f*x); }

__device__ __forceinline__ unsigned short f2bf(float f){   // RNE round
  unsigned int u = __float_as_uint(f);
  u += 0x7fffu + ((u >> 16) & 1u);
  return (unsigned short)(u >> 16);
}
__device__ __forceinline__ unsigned short f2h(float f){
  return __half_as_ushort(__float2half(f));
}
__device__ __forceinline__ int bperm(int idx, int v){
  return __builtin_amdgcn_ds_bpermute(idx, v);
}
__device__ __forceinline__ float bperm_f(int idx, int v){
  return __int_as_float(__builtin_amdgcn_ds_bpermute(idx, v));
}
__device__ __forceinline__ float elu1(float x){            // elu, x<0 branch via exp
  return x > 0.f ? x : (__expf(x) - 1.f);
}

__global__ void k_zero_i32(int* __restrict__ p, int n){
  int i = blockIdx.x*blockDim.x + threadIdx.x;
  if (i < n) p[i] = 0;
}

// hist + rank in one atomic: rank[i] = position of edge i within its dst bucket
__global__ void k_hist_rank(const int* __restrict__ dst, int* __restrict__ counts,
                            int* __restrict__ rank, int E){
  int i = blockIdx.x*blockDim.x + threadIdx.x;
  if (i < E){
    int d = dst[i];
    rank[i] = atomicAdd(&counts[d], 1);
  }
}

__global__ void k_scan_local(const int* __restrict__ counts, int* __restrict__ row_ptr,
                             int* __restrict__ bsum, int N){
  __shared__ int s[256];
  int t = threadIdx.x, g = blockIdx.x*256 + t;
  int v = (g < N) ? counts[g] : 0;
  s[t] = v; __syncthreads();
  #pragma unroll
  for (int off = 1; off < 256; off <<= 1){
    int x = 0;
    if (t >= off) x = s[t-off];
    __syncthreads();
    s[t] += x;
    __syncthreads();
  }
  if (g < N) row_ptr[g+1] = s[t];
  if (g == 0 && t == 0) row_ptr[0] = 0;
  if (t == 255) bsum[blockIdx.x] = s[255];
}

__global__ void k_scan_top(int* __restrict__ bsum, int nb){
  __shared__ int s[256];
  int t = threadIdx.x;
  int v = (t < nb) ? bsum[t] : 0;
  s[t] = v; __syncthreads();
  #pragma unroll
  for (int off = 1; off < 256; off <<= 1){
    int x = 0;
    if (t >= off) x = s[t-off];
    __syncthreads();
    s[t] += x;
    __syncthreads();
  }
  if (t < nb) bsum[t] = s[t] - v;  // exclusive block offsets
}

__global__ void k_scan_fix(int* __restrict__ row_ptr, const int* __restrict__ bsum, int N){
  int g = blockIdx.x*256 + threadIdx.x;
  if (g < N && blockIdx.x > 0) row_ptr[g+1] += bsum[blockIdx.x];
}

// atomic-free scatter: pos comes from rank captured during hist
__global__ void k_scatter2(const int* __restrict__ src, const int* __restrict__ dst,
                           const int* __restrict__ rank, const int* __restrict__ row_ptr,
                           int* __restrict__ ssrc, int E){
  int i = blockIdx.x*blockDim.x + threadIdx.x;
  if (i < E) ssrc[row_ptr[dst[i]] + rank[i]] = src[i];
}

// All three weight preps in one launch.
// Wt layout: [n][IN] bf16 (n-major). W0: 64x128; W1: 128x128; W2|rW2: 128x(64+64).
__global__ void k_wprep_all(const float* __restrict__ W0, const float* __restrict__ W1,
                            const float* __restrict__ W2, const float* __restrict__ rW2,
                            unsigned short* __restrict__ Wt0, unsigned short* __restrict__ Wt1,
                            unsigned short* __restrict__ Wt2){
  int id = blockIdx.x*256 + threadIdx.x;
  if (id < 128*64){
    int n = id/64, k = id%64;
    Wt0[n*64 + k] = f2bf(W0[k*128 + n]);
  } else if (id < 128*64 + 128*128){
    int i = id - 128*64; int n = i/128, k = i%128;
    Wt1[n*128 + k] = f2bf(W1[k*128 + n]);
  } else if (id < 128*64 + 2*128*128){
    int i = id - 128*64 - 128*128; int n = i/128, k = i%128;
    float v = (n < 64) ? W2[k*64 + n] : rW2[k*64 + (n - 64)];
    Wt2[n*128 + k] = f2bf(v);
  }
}

// MFMA GEMM: fhb[N][128](f16 row-major) = A[N][IN] @ W(128 cols via Wt).
// A source: hb bf16 (EMBED=false) or emb[feat[n]]*fv[n] converted on the fly
// (EMBED=true, IN==64). Block 256 thr = 4 waves; wave: 16 rows x 128 cols.
// Layouts (verified): A[m=lane&15][k=quad*8+j]; B[k=quad*8+j][n=lane&15];
// D: col=lane&15, row=quad*4+reg. el/er fused (16-lane butterfly per quad).
template<int IN, int H, bool EMBED>
__global__ __launch_bounds__(256) void k_gemm_mfma(
    const unsigned short* __restrict__ hb,   // [N][IN] bf16 (unused if EMBED)
    const int* __restrict__ feat, const float* __restrict__ fv,
    const float* __restrict__ embp,          // [VOCAB][64] f32
    const unsigned short* __restrict__ Wt,   // [128][IN] bf16, n-major
    const float* __restrict__ al, const float* __restrict__ ar,
    unsigned short* __restrict__ fhb,        // [N][128] f16
    float* __restrict__ elr, int N){
  constexpr int KS = IN/32;
  constexpr int LDP = IN + 8;                // +8 bf16 pad: 2-way banks only
  __shared__ unsigned short Wt_s[128*LDP];
  const int t = threadIdx.x;
  const int lane = t & 63, wid = t >> 6;
  const int l15 = lane & 15, quad = lane >> 4;
  const int row0 = blockIdx.x*64 + wid*16;

  // stage Wt -> LDS (uint4 = 8 bf16)
  for (int id = t; id < 128*(IN/8); id += 256){
    int r = id/(IN/8), seg = id%(IN/8);
    ((uint4*)(Wt_s + r*LDP))[seg] = ((const uint4*)(Wt + (size_t)r*IN))[seg];
  }
  // A fragments from global (overlaps LDS staging)
  short8 a[KS];
  int arow = row0 + l15;
  if (EMBED){
    if (arow < N){
      const float* er2 = embp + (size_t)feat[arow]*64;
      float sc = fv[arow];
      #pragma unroll
      for (int s = 0; s < KS; s++){
        const float4* p = (const float4*)(er2 + s*32 + quad*8);
        float4 v0 = p[0], v1 = p[1];
        short8 ta;
        ta[0] = (short)f2bf(v0.x*sc); ta[1] = (short)f2bf(v0.y*sc);
        ta[2] = (short)f2bf(v0.z*sc); ta[3] = (short)f2bf(v0.w*sc);
        ta[4] = (short)f2bf(v1.x*sc); ta[5] = (short)f2bf(v1.y*sc);
        ta[6] = (short)f2bf(v1.z*sc); ta[7] = (short)f2bf(v1.w*sc);
        a[s] = ta;
      }
    } else {
      #pragma unroll
      for (int s = 0; s < KS; s++) a[s] = short8{0,0,0,0,0,0,0,0};
    }
  } else {
    #pragma unroll
    for (int s = 0; s < KS; s++){
      if (arow < N) a[s] = *(const short8*)(hb + (size_t)arow*IN + s*32 + quad*8);
      else          a[s] = short8{0,0,0,0,0,0,0,0};
    }
  }
  __syncthreads();

  float4v acc[8];
  #pragma unroll
  for (int nt = 0; nt < 8; nt++) acc[nt] = float4v{0.f,0.f,0.f,0.f};
  #pragma unroll
  for (int nt = 0; nt < 8; nt++){
    #pragma unroll
    for (int s = 0; s < KS; s++){
      short8 b = *(const short8*)(Wt_s + (nt*16 + l15)*LDP + s*32 + quad*8);
      acc[nt] = __builtin_amdgcn_mfma_f32_16x16x32_bf16(a[s], b, acc[nt], 0, 0, 0);
    }
  }

  // al/ar at this lane's columns (col = nt*16 + l15); H==1: heads>0 are zero
  float alc[8], arc[8];
  #pragma unroll
  for (int nt = 0; nt < 8; nt++){
    bool hv = (H == 2) || (nt < 4);
    alc[nt] = hv ? al[nt*16 + l15] : 0.f;
    arc[nt] = hv ? ar[nt*16 + l15] : 0.f;
  }
  #pragma unroll
  for (int reg = 0; reg < 4; reg++){
    int row = row0 + quad*4 + reg;
    bool rv = row < N;
    if (rv){
      #pragma unroll
      for (int nt = 0; nt < 8; nt++)
        fhb[(size_t)row*128 + nt*16 + l15] = f2h(acc[nt][reg]);
    }
    float pel0 = 0.f, per0 = 0.f, pel1 = 0.f, per1 = 0.f;
    #pragma unroll
    for (int nt = 0; nt < 4; nt++){
      pel0 += acc[nt][reg]*alc[nt];     per0 += acc[nt][reg]*arc[nt];
      pel1 += acc[nt+4][reg]*alc[nt+4]; per1 += acc[nt+4][reg]*arc[nt+4];
    }
    #pragma unroll
    for (int off = 1; off < 16; off <<= 1){   // reduce across the 16 lanes of a quad
      pel0 += __shfl_xor(pel0, off, 64);
      pel1 += __shfl_xor(pel1, off, 64);
      per0 += __shfl_xor(per0, off, 64);
      per1 += __shfl_xor(per1, off, 64);
    }
    if (l15 == 0 && rv){
      elr[row*4+0] = pel0;
      elr[row*4+1] = (H == 2) ? pel1 : 0.f;
      elr[row*4+2] = per0;
      elr[row*4+3] = (H == 2) ? per1 : 0.f;
    }
  }
}

// One wave per dst node, SINGLE PASS: accumulate unnormalized sum(ex*F) and
// den = sum(ex); normalize in the epilogue (softmax scale is per-node scalar).
// Wave splits into groups (H=2: 4x16 lanes, H=1: 8x8); each group handles one
// edge per step, each lane gathering a uint4 (8 f16 cols) of the src row via
// 32-bit saddr addressing. Row id + unnormalized alpha broadcast via
// ds_bpermute; MAC uses fmaf((float)half,..) -> v_fma_mix. Group partials
// combined by shfl_xor butterfly.
template<int H>
__global__ __launch_bounds__(256) void k_agg(
    const unsigned short* __restrict__ fhb,  // [N][128] f16
    const float* __restrict__ elr,
    const int* __restrict__ row_ptr, const int* __restrict__ ssrc,
    const float* __restrict__ bias, const float* __restrict__ res,
    int act, int res_from_fh,
    float* __restrict__ out, int out_ld, unsigned* __restrict__ outb, int N){
  int lane = threadIdx.x & 63, wid = threadIdx.x >> 6;
  int n = blockIdx.x*4 + wid;
  if (n >= N) return;
  int beg = row_ptr[n], end = row_ptr[n+1];
  float er0 = elr[n*4+2];
  float er1 = (H == 2) ? elr[n*4+3] : 0.f;

  const char* fhbB = (const char*)fhb;           // 32-bit offsets: row = 256 B
  const int g  = (H == 2) ? (lane >> 4) : (lane >> 3);
  const int c  = (H == 2) ? (lane & 15) : (lane & 7);
  const unsigned cb = (unsigned)c << 4;          // byte offset of this lane's chunk
  const int hb4 = (H == 2 && c >= 8) ? (32 << 2) : 0;  // bperm byte base: head sel
  const int g4 = g << 2;

  float acc[8];
  #pragma unroll
  for (int k = 0; k < 8; k++) acc[k] = 0.f;
  float den0 = 0.f, den1 = 0.f;

  for (int base = beg; base < end; base += 64){
    // per-lane src + unnormalized alpha for this 64-edge window
    int s = 0; float e0 = 0.f, e1 = 0.f;
    int i = base + lane;
    if (i < end){
      s = ssrc[i];
      float2 el = *(const float2*)(elr + s*4);
      e0 = __expf(fminf(lrelu(el.x + er0), 30.f));
      if (H == 2) e1 = __expf(fminf(lrelu(el.y + er1), 30.f));
      den0 += e0; den1 += e1;
    }
    int cnt = min(64, end - base);
    if (H == 2){
      // packed alphas: ap = edges 0..31 (lanes<32: ex0, lanes>=32: ex1), ap2 = 32..63
      float e1x = __shfl_xor(e1, 32, 64);
      float e0x = __shfl_xor(e0, 32, 64);
      int ap  = __float_as_int((lane < 32) ? e0  : e1x);
      int ap2 = __float_as_int((lane < 32) ? e0x : e1);
      for (int j0 = 0; j0 < cnt; j0 += 4){       // 4 edges/step, 1 per 16-lane group
        int apx = (j0 < 32) ? ap : ap2;
        int sj = bperm(((j0 + g) << 2), s);
        unsigned off = ((unsigned)sj << 8) + cb;
        uint4 w = *(const uint4*)(fhbB + off);
        float aj = bperm_f((((j0 & 31) + g) << 2) + hb4, apx);
        const __half2* hp = (const __half2*)&w;
        #pragma unroll
        for (int q = 0; q < 4; q++){
          acc[2*q]   = fmaf((float)hp[q].x, aj, acc[2*q]);
          acc[2*q+1] = fmaf((float)hp[q].y, aj, acc[2*q+1]);
        }
      }
    } else {
      int av = __float_as_int(e0);
      for (int j0 = 0; j0 < cnt; j0 += 8){       // 8 edges/step, 1 per 8-lane group
        int sj = bperm((j0 << 2) + g4, s);
        unsigned off = ((unsigned)sj << 8) + cb; // cols 0..63 only (cb <= 112)
        uint4 w = *(const uint4*)(fhbB + off);
        float aj = bperm_f((j0 << 2) + g4, av);
        const __half2* hp = (const __half2*)&w;
        #pragma unroll
        for (int q = 0; q < 4; q++){
          acc[2*q]   = fmaf((float)hp[q].x, aj, acc[2*q]);
          acc[2*q+1] = fmaf((float)hp[q].y, aj, acc[2*q+1]);
        }
      }
    }
  }

  // denominators: full-wave butterfly
  #pragma unroll
  for (int off = 32; off >= 1; off >>= 1){
    den0 += __shfl_xor(den0, off, 64);
    if (H == 2) den1 += __shfl_xor(den1, off, 64);
  }
  float rd0 = den0 > 0.f ? 1.f/den0 : 0.f;
  float rd1 = (H == 2 && den1 > 0.f) ? 1.f/den1 : 0.f;

  // combine group partials: same c across groups holds the same columns
  #pragma unroll
  for (int k = 0; k < 8; k++){
    if (H == 1) acc[k] += __shfl_xor(acc[k], 8, 64);
    acc[k] += __shfl_xor(acc[k], 16, 64);
    acc[k] += __shfl_xor(acc[k], 32, 64);
  }

  // epilogue: lane cc < 16 (H=2) / < 8 (H=1) owns cols cc*8..cc*8+7
  if (H == 2){
    if (lane < 16){
      int cc = lane;
      float rs = (cc < 8) ? rd0 : rd1;           // head = col/64
      float o[8];
      const float4* b4 = (const float4*)bias;
      float4 ba = b4[cc*2], bb = b4[cc*2+1];
      o[0]=fmaf(acc[0],rs,ba.x); o[1]=fmaf(acc[1],rs,ba.y);
      o[2]=fmaf(acc[2],rs,ba.z); o[3]=fmaf(acc[3],rs,ba.w);
      o[4]=fmaf(acc[4],rs,bb.x); o[5]=fmaf(acc[5],rs,bb.y);
      o[6]=fmaf(acc[6],rs,bb.z); o[7]=fmaf(acc[7],rs,bb.w);
      if (res){
        const float4* r4 = (const float4*)(res + (size_t)n*128);
        float4 ra = r4[cc*2], rb = r4[cc*2+1];
        o[0]+=ra.x; o[1]+=ra.y; o[2]+=ra.z; o[3]+=ra.w;
        o[4]+=rb.x; o[5]+=rb.y; o[6]+=rb.z; o[7]+=rb.w;
      }
      if (act){
        #pragma unroll
        for (int k = 0; k < 8; k++) o[k] = elu1(o[k]);
      }
      if (out){
        float4* o4 = (float4*)(out + (size_t)n*out_ld);
        o4[cc*2]   = make_float4(o[0], o[1], o[2], o[3]);
        o4[cc*2+1] = make_float4(o[4], o[5], o[6], o[7]);
      }
      if (outb){
        uint4 ob;
        ob.x = (unsigned)f2bf(o[0]) | ((unsigned)f2bf(o[1]) << 16);
        ob.y = (unsigned)f2bf(o[2]) | ((unsigned)f2bf(o[3]) << 16);
        ob.z = (unsigned)f2bf(o[4]) | ((unsigned)f2bf(o[5]) << 16);
        ob.w = (unsigned)f2bf(o[6]) | ((unsigned)f2bf(o[7]) << 16);
        *(uint4*)(outb + (size_t)n*64 + cc*4) = ob;
      }
    }
  } else {
    if (lane < 8){
      int cc = lane;
      float o[8];
      #pragma unroll
      for (int k = 0; k < 8; k++) o[k] = fmaf(acc[k], rd0, bias[cc*8 + k]);
      if (res_from_fh){
        const uint4* fh4 = (const uint4*)fhb;
        uint4 r = fh4[(size_t)n*16 + 8 + cc];    // cols 64..127 = projected residual
        const __half2* rp = (const __half2*)&r;
        #pragma unroll
        for (int q = 0; q < 4; q++){
          o[2*q]   += (float)rp[q].x;
          o[2*q+1] += (float)rp[q].y;
        }
      }
      float4* o4 = (float4*)(out + (size_t)n*out_ld);
      o4[cc*2]   = make_float4(o[0], o[1], o[2], o[3]);
      o4[cc*2+1] = make_float4(o[4], o[5], o[6], o[7]);
    }
  }
}

extern "C" void kernel_launch(void* const* d_in, const int* in_sizes, int n_in,
                              void* d_out, int out_size, void* d_ws, size_t ws_size,
                              hipStream_t stream) {
  const int*   feat = (const int*)  d_in[0];
  const float* fv   = (const float*)d_in[1];
  const int*   src  = (const int*)  d_in[2];
  const int*   dst  = (const int*)  d_in[3];
  const float* emb  = (const float*)d_in[4];
  const float* W0   = (const float*)d_in[5];
  const float* al0  = (const float*)d_in[6];
  const float* ar0  = (const float*)d_in[7];
  const float* b0   = (const float*)d_in[8];
  const float* W1   = (const float*)d_in[9];
  const float* al1  = (const float*)d_in[10];
  const float* ar1  = (const float*)d_in[11];
  const float* b1   = (const float*)d_in[12];
  const float* W2   = (const float*)d_in[13];
  const float* al2  = (const float*)d_in[14];
  const float* ar2  = (const float*)d_in[15];
  const float* b2   = (const float*)d_in[16];
  const float* rW2  = (const float*)d_in[17];
  const int N = in_sizes[0] / 8;   // 50000
  const int E = in_sizes[2];       // 800000

  size_t off = 0;
  auto alloc = [&](size_t bytes) -> void* {
    void* p = (char*)d_ws + off;
    off = (off + bytes + 255) & ~(size_t)255;
    return p;
  };
  unsigned short* P1 = (unsigned short*)alloc((size_t)N*128*sizeof(unsigned short)); // fhb f16
  float* P2     = (float*)alloc((size_t)N*128*sizeof(float));                        // layer0 out (res for layer1)
  unsigned short* hb = (unsigned short*)alloc((size_t)N*128*sizeof(unsigned short)); // h bf16
  float* elr    = (float*)alloc((size_t)N*4*sizeof(float));
  int* row_ptr  = (int*)alloc((size_t)(N+1)*sizeof(int));
  int* counts   = (int*)alloc((size_t)N*sizeof(int));
  int* rank     = (int*)alloc((size_t)E*sizeof(int));
  int* ssrc     = (int*)alloc((size_t)E*sizeof(int));
  int* bsum     = (int*)alloc(256*sizeof(int));
  unsigned short* Wt0 = (unsigned short*)alloc((size_t)128*64*sizeof(unsigned short));
  unsigned short* Wt1 = (unsigned short*)alloc((size_t)128*128*sizeof(unsigned short));
  unsigned short* Wt2 = (unsigned short*)alloc((size_t)128*128*sizeof(unsigned short));

  int nb1 = (N + 255) / 256;
  // CSR build (rank captured in hist atomic; scatter atomic-free)
  k_zero_i32<<<(N + 255)/256, 256, 0, stream>>>(counts, N);
  k_hist_rank<<<(E + 255)/256, 256, 0, stream>>>(dst, counts, rank, E);
  k_scan_local<<<nb1, 256, 0, stream>>>(counts, row_ptr, bsum, N);
  k_scan_top<<<1, 256, 0, stream>>>(bsum, nb1);
  k_scan_fix<<<nb1, 256, 0, stream>>>(row_ptr, bsum, N);
  k_scatter2<<<(E + 255)/256, 256, 0, stream>>>(src, dst, rank, row_ptr, ssrc, E);
  // weight transpose+bf16 prep (single launch)
  k_wprep_all<<<(128*64 + 2*128*128 + 255)/256, 256, 0, stream>>>(
      W0, W1, W2, rW2, Wt0, Wt1, Wt2);

  int gt = (N + 63)/64;
  int nagg = (N + 3)/4;
  // layer 0: in=64, H=2, embed fused into A-load, no residual, elu
  k_gemm_mfma<64,2,true><<<gt, 256, 0, stream>>>(nullptr, feat, fv, emb,
                                                 Wt0, al0, ar0, P1, elr, N);
  k_agg<2><<<nagg, 256, 0, stream>>>(P1, elr, row_ptr, ssrc, b0, nullptr,
                                     1, 0, P2, 128, (unsigned*)hb, N);
  // layer 1: in=128, H=2, identity residual, elu; float out unused -> skip store
  k_gemm_mfma<128,2,false><<<gt, 256, 0, stream>>>(hb, nullptr, nullptr, nullptr,
                                                   Wt1, al1, ar1, P1, elr, N);
  k_agg<2><<<nagg, 256, 0, stream>>>(P1, elr, row_ptr, ssrc, b1, P2,
                                     1, 0, nullptr, 128, (unsigned*)hb, N);
  // layer 2: in=128, H=1, projected residual (fh cols 64..127 = h@resW2), no act
  k_gemm_mfma<128,1,false><<<gt, 256, 0, stream>>>(hb, nullptr, nullptr, nullptr,
                                                   Wt2, al2, ar2, P1, elr, N);
  k_agg<1><<<nagg, 256, 0, stream>>>(P1, elr, row_ptr, ssrc, b2, nullptr,
                                     0, 1, (float*)d_out, 64, nullptr, N);
}